// Round 1
// baseline (312.572 us; speedup 1.0000x reference)
//
#include <hip/hip_runtime.h>

// Problem constants
#define HW    16
#define CIN   8
#define COUT  8
#define NB    2048   // n_back (k), innermost dim of w tensors
#define NOUT  2048   // H*W*COUT
#define NDIM  2048   // H*W*CIN

// Output flat offsets (floats) in d_out: [w_u_, b_u_, w_l_, b_l_]
#define OFF_BU  16777216ull              // 4*2048*2048
#define OFF_WL  16785408ull              // OFF_BU + 4*2048
#define OFF_BL  33562624ull              // OFF_WL + 4*2048*2048

// One wave (64 threads) per block.
// block: x = hi*4 + q (64), y = k-tile (32), z = b (4)
// lane  = k within tile. Wave computes out[b, (hi, q*4..q*4+3, ci=0..7), k]
// = sum over (dh,dw,co) of kernel[1-dh,1-dw,ci,co] * w_in[b,(hi+dh,wi+dw,co),k]
__global__ __launch_bounds__(64) void conv_back_kernel(
    const float* __restrict__ win,   // (4, 2048, 2048)  w_out_u or w_out_l
    const float* __restrict__ kern,  // (3,3,8,8)
    const float* __restrict__ bias,  // (8)
    float* __restrict__ wout,        // (4, 2048, 2048) output region
    float* __restrict__ bias_ws)     // (4, 2048) partial bias accumulation
{
    const int lane = threadIdx.x;          // 0..63
    const int hq   = blockIdx.x;           // 0..63
    const int hi   = hq >> 2;
    const int q    = hq & 3;
    const int kt   = blockIdx.y;           // 0..31
    const int b    = blockIdx.z;           // 0..3
    const int k    = (kt << 6) + lane;

    const float* wb = win + ((size_t)b * NOUT) * NB + k;   // + o*NB

    float acc[8][4];
    #pragma unroll
    for (int ci = 0; ci < 8; ++ci)
        #pragma unroll
        for (int w4 = 0; w4 < 4; ++w4) acc[ci][w4] = 0.f;
    float pb = 0.f;

    #pragma unroll
    for (int dh = -1; dh <= 1; ++dh) {
        const int ho = hi + dh;
        const bool hok = ((unsigned)ho < HW);
        #pragma unroll
        for (int dw = -1; dw <= 1; ++dw) {
            #pragma unroll
            for (int co = 0; co < 8; ++co) {
                float u[4];
                #pragma unroll
                for (int w4 = 0; w4 < 4; ++w4) {
                    const int wo = q * 4 + w4 + dw;
                    const bool ok = hok && ((unsigned)wo < HW);
                    u[w4] = ok ? wb[(size_t)((ho * HW + wo) * COUT + co) * NB] : 0.f;
                }
                if (dh == 0 && dw == 0) {
                    // this wave owns o = (hi, q*4+w4, co) exactly once across the grid
                    pb += bias[co] * (u[0] + u[1] + u[2] + u[3]);
                }
                // kernel[kh=1-dh][kw=1-dw][ci][co]
                const int kb = ((1 - dh) * 3 + (1 - dw)) * 64 + co;
                #pragma unroll
                for (int ci = 0; ci < 8; ++ci) {
                    const float Kv = kern[kb + ci * 8];
                    #pragma unroll
                    for (int w4 = 0; w4 < 4; ++w4)
                        acc[ci][w4] += Kv * u[w4];
                }
            }
        }
    }

    #pragma unroll
    for (int ci = 0; ci < 8; ++ci)
        #pragma unroll
        for (int w4 = 0; w4 < 4; ++w4) {
            const int i = (hi * HW + q * 4 + w4) * CIN + ci;
            wout[((size_t)b * NDIM + i) * NB + k] = acc[ci][w4];
        }

    atomicAdd(&bias_ws[b * NB + k], pb);
}

// b_out_ = b_in + ws ; 16384 elements total (2 ul * 4 b * 2048 k)
__global__ void bias_finalize(const float* __restrict__ bu,
                              const float* __restrict__ bl,
                              const float* __restrict__ ws,
                              float* __restrict__ out)
{
    const int idx = blockIdx.x * blockDim.x + threadIdx.x;   // 0..16383
    const int ul  = idx >> 13;
    const int r   = idx & 8191;                              // b*2048 + k
    const float* bin = ul ? bl : bu;
    const size_t off = ul ? OFF_BL : OFF_BU;
    out[off + r] = bin[r] + ws[(size_t)ul * 8192 + r];
}

extern "C" void kernel_launch(void* const* d_in, const int* in_sizes, int n_in,
                              void* d_out, int out_size, void* d_ws, size_t ws_size,
                              hipStream_t stream) {
    // inputs: 0=x (unused), 1=kernel, 2=bias, 3=w_out_u, 4=b_out_u, 5=w_out_l, 6=b_out_l
    const float* kern = (const float*)d_in[1];
    const float* bias = (const float*)d_in[2];
    const float* wu   = (const float*)d_in[3];
    const float* bu   = (const float*)d_in[4];
    const float* wl   = (const float*)d_in[5];
    const float* bl   = (const float*)d_in[6];
    float* out = (float*)d_out;
    float* ws  = (float*)d_ws;

    // zero the 64 KB bias-partial region every call (graph replays re-run this node)
    hipMemsetAsync(ws, 0, 2ull * 4 * NB * sizeof(float), stream);

    dim3 grid(64, 32, 4), block(64);
    conv_back_kernel<<<grid, block, 0, stream>>>(wu, kern, bias, out,            ws);
    conv_back_kernel<<<grid, block, 0, stream>>>(wl, kern, bias, out + OFF_WL,   ws + 8192);
    bias_finalize<<<64, 256, 0, stream>>>(bu, bl, ws, out);
}

// Round 3
// 152.014 us; speedup vs baseline: 2.0562x; 2.0562x over previous
//
#include <hip/hip_runtime.h>

// Problem constants
#define NB    2048   // n_back (k), innermost dim
#define NB2   1024   // NB/2 in float2 units
#define NOUT  2048   // H*W*COUT
#define NDIM  2048   // H*W*CIN

// Output flat offsets (floats) in d_out: [w_u_, b_u_, w_l_, b_l_]
#define OFF_BU  16777216ull              // 4*2048*2048
#define OFF_WL  16785408ull              // OFF_BU + 4*2048
#define OFF_BL  33562624ull              // OFF_WL + 4*2048*2048

typedef float f32x2 __attribute__((ext_vector_type(2)));

// Merged kernel: grid.z selects (tensor t, batch b). Each thread owns a
// float2 of k (2 consecutive k) and a (hi, wi-pair) spatial tile, all 8 ci.
// out[b,(hi,wi,ci),k] = sum_{dh,dw,co} kern[1-dh,1-dw,ci,co] * win[b,(hi+dh,wi+dw,co),k]
__global__ __launch_bounds__(256, 4) void conv_back_kernel(
    const float* __restrict__ wu,
    const float* __restrict__ wl,
    const float* __restrict__ kern,   // (3,3,8,8) [kh][kw][ci][co]
    const float* __restrict__ bias,   // (8)
    float* __restrict__ out,          // full d_out base
    float* __restrict__ bias_ws)      // (2,4,2048) partial bias sums
{
    const int tid = threadIdx.x;             // 0..255
    const int x   = blockIdx.x;              // 0..127
    const int hi  = x >> 3;
    const int wp  = (x & 7) * 2;             // wi pair base
    const int kh2 = blockIdx.y * 256 + tid;  // float2 index over k, 0..1023
    const int z   = blockIdx.z;              // 0..7
    const int t   = z >> 2;                  // 0 = upper, 1 = lower
    const int b   = z & 3;

    const f32x2* win2 = (const f32x2*)(t ? wl : wu) + (size_t)b * NOUT * NB2 + kh2;
    f32x2* wout2 = (f32x2*)(out + (t ? OFF_WL : 0)) + (size_t)b * NDIM * NB2 + kh2;

    f32x2 acc[8][2];
    #pragma unroll
    for (int ci = 0; ci < 8; ++ci) {
        acc[ci][0] = (f32x2)(0.f, 0.f);
        acc[ci][1] = (f32x2)(0.f, 0.f);
    }
    f32x2 pb = (f32x2)(0.f, 0.f);

    #pragma unroll
    for (int dh = -1; dh <= 1; ++dh) {
        const int ho = hi + dh;
        if ((unsigned)ho < 16u) {            // wave-uniform branch
            const f32x2* rowb = win2 + (size_t)(ho * 16) * 8 * NB2;
            #pragma unroll
            for (int dw = -1; dw <= 1; ++dw) {
                const int wo0 = wp + dw;
                const int wo1 = wp + 1 + dw;
                const bool v0 = (unsigned)wo0 < 16u;   // uniform
                const bool v1 = (unsigned)wo1 < 16u;   // uniform
                #pragma unroll
                for (int co = 0; co < 8; ++co) {
                    f32x2 u0 = (f32x2)(0.f, 0.f);
                    f32x2 u1 = (f32x2)(0.f, 0.f);
                    if (v0) u0 = rowb[(size_t)(wo0 * 8 + co) * NB2];
                    if (v1) u1 = rowb[(size_t)(wo1 * 8 + co) * NB2];
                    if (dh == 0 && dw == 0) {
                        // each o=(hi,wp+w4,co) owned exactly once across grid
                        const float bv = bias[co];
                        pb.x += bv * (u0.x + u1.x);
                        pb.y += bv * (u0.y + u1.y);
                    }
                    const int kb = ((1 - dh) * 3 + (1 - dw)) * 64 + co;
                    #pragma unroll
                    for (int ci = 0; ci < 8; ++ci) {
                        const float Kv = kern[kb + ci * 8];   // uniform -> SGPR
                        acc[ci][0].x += Kv * u0.x;
                        acc[ci][0].y += Kv * u0.y;
                        acc[ci][1].x += Kv * u1.x;
                        acc[ci][1].y += Kv * u1.y;
                    }
                }
            }
        }
    }

    #pragma unroll
    for (int ci = 0; ci < 8; ++ci)
        #pragma unroll
        for (int w4 = 0; w4 < 2; ++w4) {
            const int i = (hi * 16 + wp + w4) * 8 + ci;
            __builtin_nontemporal_store(acc[ci][w4], &wout2[(size_t)i * NB2]);
        }

    float* bws = bias_ws + t * 8192 + b * 2048 + 2 * kh2;
    atomicAdd(bws,     pb.x);
    atomicAdd(bws + 1, pb.y);
}

// b_out_ = b_in + ws ; 16384 outputs (2 ul * 4 b * 2048 k)
__global__ void bias_finalize(const float* __restrict__ bu,
                              const float* __restrict__ bl,
                              const float* __restrict__ ws,
                              float* __restrict__ out)
{
    const int idx = blockIdx.x * blockDim.x + threadIdx.x;   // 0..16383
    const int ul  = idx >> 13;
    const int r   = idx & 8191;                              // b*2048 + k
    const float* bin = ul ? bl : bu;
    const size_t off = ul ? OFF_BL : OFF_BU;
    out[off + r] = bin[r] + ws[(size_t)ul * 8192 + r];
}

extern "C" void kernel_launch(void* const* d_in, const int* in_sizes, int n_in,
                              void* d_out, int out_size, void* d_ws, size_t ws_size,
                              hipStream_t stream) {
    // inputs: 0=x (unused), 1=kernel, 2=bias, 3=w_out_u, 4=b_out_u, 5=w_out_l, 6=b_out_l
    const float* kern = (const float*)d_in[1];
    const float* bias = (const float*)d_in[2];
    const float* wu   = (const float*)d_in[3];
    const float* bu   = (const float*)d_in[4];
    const float* wl   = (const float*)d_in[5];
    const float* bl   = (const float*)d_in[6];
    float* out = (float*)d_out;
    float* ws  = (float*)d_ws;

    // zero the 64 KB bias-partial region (graph replays re-run this node)
    (void)hipMemsetAsync(ws, 0, 2ull * 4 * NB * sizeof(float), stream);

    dim3 grid(128, 4, 8), block(256);
    conv_back_kernel<<<grid, block, 0, stream>>>(wu, wl, kern, bias, out, ws);
    bias_finalize<<<64, 256, 0, stream>>>(bu, bl, ws, out);
}